// Round 4
// baseline (428.237 us; speedup 1.0000x reference)
//
#include <hip/hip_runtime.h>

#define IMG_B 32
#define IMG_HW (512 * 512)
#define NBINS 256
#define BPI 64                       // blocks per image
#define NTHREADS 256
#define CHUNK (IMG_HW / BPI)         // 4096 pixels per block
#define NWAVES (NTHREADS / 64)
#define HIST_WORDS (IMG_B * BPI * NBINS)   // 2M u32 = 8 MB? no: 2048*256*4B = 2 MB

// ws layout (u32 words):
//   [0, HIST_WORDS)             per-block histograms, ws[blk*256 + bin]
//   [HIST_WORDS, +32)           per-image entropy (as float)
//   [HIST_WORDS+32, +64)        per-image done-counters
//   [HIST_WORDS+64]             global image-done counter
// The memset node zeroes words [HIST_WORDS, HIST_WORDS+128) (counters + ent).

// ---------------------------------------------------------------------------
// Fused kernel. Phase 1 (all 2048 blocks): per-wave privatized LDS uint
// histogram of the block's 4096-pixel chunk (counts only — H == cnt/N to ~1
// ulp; bin-0 "+N" is dead since y >= 0.0625 -> cnt[0] == 0). Phase 2 (last
// block per image): sum the image's 64 block-histograms, entropy term per
// bin, block-reduce, store per-image entropy. Phase 3 (last image done):
// wave-reduce the 32 entropies, write out = sign * mean. 2 graph nodes total.
// ---------------------------------------------------------------------------
__global__ __launch_bounds__(NTHREADS)
void ie_fused_kernel(const float* __restrict__ x, unsigned* __restrict__ ws,
                     const int* __restrict__ sign, float* __restrict__ out) {
    __shared__ unsigned h[NWAVES][NBINS];
    __shared__ unsigned s_old;
    __shared__ unsigned s_gold;
    __shared__ float red[NWAVES];

    const int tid  = threadIdx.x;
    const int wave = tid >> 6;
    const int blk  = blockIdx.x;
    const int img  = blk / BPI;
    const int part = blk % BPI;

    float* ent      = (float*)(ws + HIST_WORDS);
    unsigned* ictr  = ws + HIST_WORDS + 32;
    unsigned* gctr  = ws + HIST_WORDS + 64;

    for (int i = tid; i < NWAVES * NBINS; i += NTHREADS)
        (&h[0][0])[i] = 0u;
    __syncthreads();

    const float* base = x + (size_t)img * 3u * IMG_HW + (size_t)part * CHUNK;
    const float4* r4 = (const float4*)(base);
    const float4* g4 = (const float4*)(base + IMG_HW);
    const float4* b4 = (const float4*)(base + 2 * IMG_HW);

    const float interval = 1.0f / 255.0f;
    const float eps = 0.5f * interval;

    const int nvec = CHUNK / 4;  // 1024 float4 per channel
    for (int i = tid; i < nvec; i += NTHREADS) {
        float4 r = r4[i];
        float4 g = g4[i];
        float4 b = b4[i];
        float ys[4];
        ys[0] = 0.257f * r.x + 0.564f * g.x + 0.098f * b.x + 0.0625f;
        ys[1] = 0.257f * r.y + 0.564f * g.y + 0.098f * b.y + 0.0625f;
        ys[2] = 0.257f * r.z + 0.564f * g.z + 0.098f * b.z + 0.0625f;
        ys[3] = 0.257f * r.w + 0.564f * g.w + 0.098f * b.w + 0.0625f;
#pragma unroll
        for (int k = 0; k < 4; ++k) {
            float y = ys[k];
            float fidx = rintf(y * 255.0f);     // round-half-to-even == jnp.round
            int idx = (int)fidx;
            float v = fidx * interval;
            bool inb = (y > v - eps) && (y < v + eps) && (idx >= 0) && (idx <= NBINS - 1);
            if (inb) atomicAdd(&h[wave][idx], 1u);
        }
    }
    __syncthreads();

    unsigned c = 0;
#pragma unroll
    for (int w = 0; w < NWAVES; ++w) c += h[w][tid];
    ws[(size_t)blk * NBINS + tid] = c;

    // ---- per-image completion handshake ----
    __threadfence();                          // release our histogram store
    if (tid == 0) s_old = atomicAdd(&ictr[img], 1u);
    __syncthreads();
    if (s_old != BPI - 1) return;

    // ---- phase 2: this is the last block of its image ----
    __threadfence();                          // acquire other blocks' stores
    const unsigned* p = ws + (size_t)img * BPI * NBINS + tid;
    unsigned cc = 0;
#pragma unroll 8
    for (int b = 0; b < BPI; ++b) cc += p[(size_t)b * NBINS];

    const float Nf = (float)IMG_HW;
    float acc = 0.0f;
    if (cc >= 1u) {
        float H = (float)cc / Nf;
        acc = -H * log2f(H);
    }
#pragma unroll
    for (int off = 32; off > 0; off >>= 1)
        acc += __shfl_down(acc, off, 64);
    if ((tid & 63) == 0) red[tid >> 6] = acc;
    __syncthreads();
    if (tid == 0) {
        float tot = 0.0f;
#pragma unroll
        for (int w = 0; w < NWAVES; ++w) tot += red[w];
        ent[img] = tot;
        __threadfence();                      // release per-image entropy
        s_gold = atomicAdd(gctr, 1u);
    }
    __syncthreads();
    if (s_gold != IMG_B - 1) return;

    // ---- phase 3: all images done; wave 0 reduces the 32 entropies ----
    if (tid < 64) {
        __threadfence();                      // acquire all ent[] stores
        float v = (tid < IMG_B) ? ent[tid] : 0.0f;
#pragma unroll
        for (int off = 16; off > 0; off >>= 1)
            v += __shfl_down(v, off, 64);
        if (tid == 0)
            out[0] = (float)sign[0] * (v * (1.0f / (float)IMG_B));
    }
}

extern "C" void kernel_launch(void* const* d_in, const int* in_sizes, int n_in,
                              void* d_out, int out_size, void* d_ws, size_t ws_size,
                              hipStream_t stream) {
    const float* x  = (const float*)d_in[0];
    const int* sign = (const int*)d_in[1];
    float* out      = (float*)d_out;
    unsigned* ws    = (unsigned*)d_ws;   // needs (HIST_WORDS + 128) * 4 bytes ≈ 2 MB

    // zero the counters (+ ent scratch) — ws is poisoned 0xAA before every call
    hipMemsetAsync(ws + HIST_WORDS, 0, 128 * sizeof(unsigned), stream);
    ie_fused_kernel<<<IMG_B * BPI, NTHREADS, 0, stream>>>(x, ws, sign, out);
}

// Round 5
// 157.422 us; speedup vs baseline: 2.7203x; 2.7203x over previous
//
#include <hip/hip_runtime.h>

#define IMG_B 32
#define IMG_HW (512 * 512)
#define NBINS 256
#define BPI 64                       // blocks per image
#define NTHREADS 256
#define CHUNK (IMG_HW / BPI)         // 4096 pixels per block
#define NWAVES (NTHREADS / 64)

// ws layout (u32 words) — all cross-block data accessed ONLY via device-scope
// atomics (coherent point, bypasses the non-coherent per-XCD L2s; no fences):
#define GH_OFF   0                       // [0, 32*256) per-image histograms
#define ENT_OFF  (IMG_B * NBINS)        // 32 floats: per-image entropy
#define ICTR_OFF (ENT_OFF + IMG_B)      // 32 per-image done-counters
#define GCTR_OFF (ICTR_OFF + IMG_B)     // 1 global image-done counter
#define WS_WORDS (GCTR_OFF + 1)

// ---------------------------------------------------------------------------
// Fused kernel, fence-free. Phase 1 (2048 blocks): LDS per-wave uint hist of
// a 4096-pixel chunk (counts only — H == cnt/N to ~1 ulp; bin-0 "+N" is dead
// since y >= 0.0625 -> cnt[0]==0). Block-reduce, atomicAdd bins into the
// per-image global hist. __syncthreads drains vmcnt(0) in every wave, so all
// bin-atomics are complete before tid0 bumps the image counter (relaxed).
// Phase 2 (last block per image): agent-scope atomic loads of the 256 bins,
// entropy, atomic-store ent[img], RELEASE-bump global counter. Phase 3
// (last image): reduce 32 entropies, write out = sign * mean.
// ---------------------------------------------------------------------------
__global__ __launch_bounds__(NTHREADS)
void ie_fused_kernel(const float* __restrict__ x, unsigned* __restrict__ ws,
                     const int* __restrict__ sign, float* __restrict__ out) {
    __shared__ unsigned h[NWAVES][NBINS];
    __shared__ unsigned s_old;
    __shared__ unsigned s_gold;
    __shared__ float red[NWAVES];

    const int tid  = threadIdx.x;
    const int wave = tid >> 6;
    const int blk  = blockIdx.x;
    const int img  = blk / BPI;
    const int part = blk % BPI;

    unsigned* ghist = ws + GH_OFF + (size_t)img * NBINS;
    float*    ent   = (float*)(ws + ENT_OFF);
    unsigned* ictr  = ws + ICTR_OFF;
    unsigned* gctr  = ws + GCTR_OFF;

    for (int i = tid; i < NWAVES * NBINS; i += NTHREADS)
        (&h[0][0])[i] = 0u;
    __syncthreads();

    const float* base = x + (size_t)img * 3u * IMG_HW + (size_t)part * CHUNK;
    const float4* r4 = (const float4*)(base);
    const float4* g4 = (const float4*)(base + IMG_HW);
    const float4* b4 = (const float4*)(base + 2 * IMG_HW);

    const float interval = 1.0f / 255.0f;
    const float eps = 0.5f * interval;

    const int nvec = CHUNK / 4;  // 1024 float4 per channel
    for (int i = tid; i < nvec; i += NTHREADS) {
        float4 r = r4[i];
        float4 g = g4[i];
        float4 b = b4[i];
        float ys[4];
        ys[0] = 0.257f * r.x + 0.564f * g.x + 0.098f * b.x + 0.0625f;
        ys[1] = 0.257f * r.y + 0.564f * g.y + 0.098f * b.y + 0.0625f;
        ys[2] = 0.257f * r.z + 0.564f * g.z + 0.098f * b.z + 0.0625f;
        ys[3] = 0.257f * r.w + 0.564f * g.w + 0.098f * b.w + 0.0625f;
#pragma unroll
        for (int k = 0; k < 4; ++k) {
            float y = ys[k];
            float fidx = rintf(y * 255.0f);     // round-half-to-even == jnp.round
            int idx = (int)fidx;
            float v = fidx * interval;
            bool inb = (y > v - eps) && (y < v + eps) && (idx >= 0) && (idx <= NBINS - 1);
            if (inb) atomicAdd(&h[wave][idx], 1u);
        }
    }
    __syncthreads();

    unsigned c = 0;
#pragma unroll
    for (int w = 0; w < NWAVES; ++w) c += h[w][tid];
    if (c) atomicAdd(&ghist[tid], c);   // device-scope, coherent point, no fence

    __syncthreads();                    // every wave: s_waitcnt vmcnt(0) -> all
                                        // bin-atomics of this block complete
    if (tid == 0)
        s_old = __hip_atomic_fetch_add(&ictr[img], 1u,
                                       __ATOMIC_RELAXED, __HIP_MEMORY_SCOPE_AGENT);
    __syncthreads();
    if (s_old != BPI - 1) return;

    // ---- phase 2: last block of this image ----
    unsigned cc = __hip_atomic_load(&ghist[tid],
                                    __ATOMIC_RELAXED, __HIP_MEMORY_SCOPE_AGENT);
    const float Nf = (float)IMG_HW;
    float acc = 0.0f;
    if (cc >= 1u) {
        float H = (float)cc / Nf;
        acc = -H * log2f(H);
    }
#pragma unroll
    for (int off = 32; off > 0; off >>= 1)
        acc += __shfl_down(acc, off, 64);
    if ((tid & 63) == 0) red[tid >> 6] = acc;
    __syncthreads();
    if (tid == 0) {
        float tot = 0.0f;
#pragma unroll
        for (int w = 0; w < NWAVES; ++w) tot += red[w];
        __hip_atomic_store(&ent[img], tot,
                           __ATOMIC_RELAXED, __HIP_MEMORY_SCOPE_AGENT);
        // RELEASE: s_waitcnt vmcnt(0) before the add -> ent store complete
        s_gold = __hip_atomic_fetch_add(gctr, 1u,
                                        __ATOMIC_RELEASE, __HIP_MEMORY_SCOPE_AGENT);
    }
    __syncthreads();
    if (s_gold != IMG_B - 1) return;

    // ---- phase 3: all images done; wave 0 reduces the 32 entropies ----
    if (tid < 64) {
        float v = 0.0f;
        if (tid < IMG_B)
            v = __hip_atomic_load(&ent[tid],
                                  __ATOMIC_RELAXED, __HIP_MEMORY_SCOPE_AGENT);
#pragma unroll
        for (int off = 16; off > 0; off >>= 1)
            v += __shfl_down(v, off, 64);
        if (tid == 0)
            out[0] = (float)sign[0] * (v * (1.0f / (float)IMG_B));
    }
}

extern "C" void kernel_launch(void* const* d_in, const int* in_sizes, int n_in,
                              void* d_out, int out_size, void* d_ws, size_t ws_size,
                              hipStream_t stream) {
    const float* x  = (const float*)d_in[0];
    const int* sign = (const int*)d_in[1];
    float* out      = (float*)d_out;
    unsigned* ws    = (unsigned*)d_ws;   // needs WS_WORDS*4 ≈ 33 KB scratch

    // zero hist + counters (ws is poisoned 0xAA before every call)
    hipMemsetAsync(ws, 0, WS_WORDS * sizeof(unsigned), stream);
    ie_fused_kernel<<<IMG_B * BPI, NTHREADS, 0, stream>>>(x, ws, sign, out);
}

// Round 7
// 138.700 us; speedup vs baseline: 3.0875x; 1.1350x over previous
//
#include <hip/hip_runtime.h>

#define IMG_B 32
#define IMG_HW (512 * 512)
#define NBINS 256
#define BPI 64                       // blocks per image
#define NTHREADS 256
#define CHUNK (IMG_HW / BPI)         // 4096 pixels per block
#define NWAVES (NTHREADS / 64)

typedef float nt_f4 __attribute__((ext_vector_type(4)));  // builtin-compatible float4

// ---------------------------------------------------------------------------
// Kernel 1: per-block 256-bin count histogram. Counts only — the reference's
// H = S/(pixel*N) with pixel = detach(S/cnt) equals cnt/N to ~1 ulp, and the
// bin-0 "+N" offset is dead (y >= 0.0625 -> idx >= 16 -> cnt[0] == 0 always).
// Per-wave privatized LDS uint histograms (native ds_add_u32, no CAS loop),
// block-reduce, plain coalesced store to ws[blk*256 + bin]. No global atomics.
// Block 0 also zeroes out[0] (d_out is poisoned 0xAA each call); the dispatch
// boundary orders this before kernel 2's atomicAdds — no memset node needed.
// Grid: IMG_B*BPI = 2048 blocks x 256 thr = 8 blocks/CU = 32 waves/CU (max).
// Input loads are non-temporal: 100.7 MB read-once stream, no reuse.
// ---------------------------------------------------------------------------
__global__ __launch_bounds__(NTHREADS)
void ie_hist_kernel(const float* __restrict__ x, unsigned* __restrict__ ws,
                    float* __restrict__ out) {
    __shared__ unsigned h[NWAVES][NBINS];

    const int tid  = threadIdx.x;
    const int wave = tid >> 6;
    const int blk  = blockIdx.x;
    const int img  = blk / BPI;
    const int part = blk % BPI;

    if (blk == 0 && tid == 0) out[0] = 0.0f;

    for (int i = tid; i < NWAVES * NBINS; i += NTHREADS)
        (&h[0][0])[i] = 0u;
    __syncthreads();

    const float* base = x + (size_t)img * 3u * IMG_HW + (size_t)part * CHUNK;
    const nt_f4* r4 = (const nt_f4*)(base);
    const nt_f4* g4 = (const nt_f4*)(base + IMG_HW);
    const nt_f4* b4 = (const nt_f4*)(base + 2 * IMG_HW);

    const float interval = 1.0f / 255.0f;
    const float eps = 0.5f * interval;

    const int nvec = CHUNK / 4;  // 1024 float4 per channel
    for (int i = tid; i < nvec; i += NTHREADS) {
        nt_f4 r = __builtin_nontemporal_load(&r4[i]);
        nt_f4 g = __builtin_nontemporal_load(&g4[i]);
        nt_f4 b = __builtin_nontemporal_load(&b4[i]);
        nt_f4 ys = 0.257f * r + 0.564f * g + 0.098f * b + 0.0625f;
#pragma unroll
        for (int k = 0; k < 4; ++k) {
            float y = ys[k];
            float fidx = rintf(y * 255.0f);     // round-half-to-even == jnp.round
            int idx = (int)fidx;
            float v = fidx * interval;
            bool inb = (y > v - eps) && (y < v + eps) && (idx >= 0) && (idx <= NBINS - 1);
            if (inb) atomicAdd(&h[wave][idx], 1u);
        }
    }
    __syncthreads();

    unsigned c = 0;
#pragma unroll
    for (int w = 0; w < NWAVES; ++w) c += h[w][tid];
    ws[(size_t)blk * NBINS + tid] = c;
}

// ---------------------------------------------------------------------------
// Kernel 2: entropy. One block per image (32 blocks x 256 thr). Thread t sums
// the 64 block-histogram entries for bin t (coalesced: wave reads consecutive
// bins), computes -H*log2(H), block-reduces, then a single device-scope
// atomicAdd of sign*ent/IMG_B into out[0] (zeroed by kernel 1).
// ---------------------------------------------------------------------------
__global__ __launch_bounds__(NTHREADS)
void ie_entropy_kernel(const unsigned* __restrict__ ws, const int* __restrict__ sign,
                       float* __restrict__ out) {
    const int tid = threadIdx.x;
    const int img = blockIdx.x;
    const float Nf = (float)IMG_HW;

    const unsigned* p = ws + (size_t)img * BPI * NBINS + tid;
    unsigned c = 0;
#pragma unroll 8
    for (int b = 0; b < BPI; ++b) c += p[(size_t)b * NBINS];

    float acc = 0.0f;
    if (c >= 1u) {
        float H = (float)c / Nf;
        acc = -H * log2f(H);
    }

    __shared__ float red[NWAVES];
#pragma unroll
    for (int off = 32; off > 0; off >>= 1)
        acc += __shfl_down(acc, off, 64);
    if ((tid & 63) == 0) red[tid >> 6] = acc;
    __syncthreads();
    if (tid == 0) {
        float tot = 0.0f;
#pragma unroll
        for (int w = 0; w < NWAVES; ++w) tot += red[w];
        atomicAdd(out, (float)sign[0] * (tot / (float)IMG_B));
    }
}

extern "C" void kernel_launch(void* const* d_in, const int* in_sizes, int n_in,
                              void* d_out, int out_size, void* d_ws, size_t ws_size,
                              hipStream_t stream) {
    const float* x  = (const float*)d_in[0];
    const int* sign = (const int*)d_in[1];
    float* out      = (float*)d_out;
    unsigned* ws    = (unsigned*)d_ws;   // needs IMG_B*BPI*NBINS*4 = 2 MB scratch

    ie_hist_kernel<<<IMG_B * BPI, NTHREADS, 0, stream>>>(x, ws, out);
    ie_entropy_kernel<<<IMG_B, NTHREADS, 0, stream>>>(ws, sign, out);
}